// Round 1
// baseline (4452.286 us; speedup 1.0000x reference)
//
#include <hip/hip_runtime.h>
#include <cstdint>
#include <cstddef>

#define KNB 20
#define NPTS 8192
#define BATCH 2
#define TOTAL (BATCH * NPTS)

// ---------------------------------------------------------------------------
// K1: pointwise conv 3->64 + relu
// ---------------------------------------------------------------------------
__global__ __launch_bounds__(256) void k_conv(const float* __restrict__ pts,
                                              const float* __restrict__ w,
                                              const float* __restrict__ b,
                                              float* __restrict__ x0) {
  int gid = blockIdx.x * 256 + threadIdx.x;
  if (gid >= TOTAL * 64) return;
  int p = gid >> 6, c = gid & 63;
  float px = pts[p * 3 + 0], py = pts[p * 3 + 1], pz = pts[p * 3 + 2];
  float acc = b[c] + px * w[c] + py * w[64 + c] + pz * w[128 + c];
  x0[gid] = fmaxf(acc, 0.f);
}

// ---------------------------------------------------------------------------
// K2: brute-force KNN top-20 (squared dist, stable ties like lax.top_k).
// One thread per query; candidates staged through LDS in tiles of 256.
// Sorted insertion kept fully register-resident (static unrolled indices).
// ---------------------------------------------------------------------------
__global__ __launch_bounds__(256) void k_knn(const float* __restrict__ pts,
                                             int* __restrict__ idxbuf) {
  __shared__ float sp[768];
  int q = blockIdx.x * 256 + threadIdx.x;      // 0..16383, block-uniform batch
  int b = q >> 13;
  const float* pbase = pts + (size_t)b * NPTS * 3;
  float qx = pts[q * 3 + 0], qy = pts[q * 3 + 1], qz = pts[q * 3 + 2];

  float dist[KNB];
  int id[KNB];
#pragma unroll
  for (int j = 0; j < KNB; j++) { dist[j] = 3.402823466e38f; id[j] = 0; }

  for (int tile = 0; tile < NPTS; tile += 256) {
    __syncthreads();
    int t = threadIdx.x;
    sp[t]       = pbase[tile * 3 + t];
    sp[t + 256] = pbase[tile * 3 + t + 256];
    sp[t + 512] = pbase[tile * 3 + t + 512];
    __syncthreads();
    for (int c = 0; c < 256; c++) {
      float dx = qx - sp[c * 3 + 0];
      float dy = qy - sp[c * 3 + 1];
      float dz = qz - sp[c * 3 + 2];
      float d2 = dx * dx + dy * dy + dz * dz;
      if (d2 < dist[KNB - 1]) {
        int cid = tile + c;
        // branchless sorted insert (ascending), strict < keeps lax.top_k
        // stable tie-breaking (earlier index wins).
#pragma unroll
        for (int j = KNB - 1; j >= 0; j--) {
          bool cj = d2 < dist[j];
          bool cjm1 = (j > 0) && (d2 < dist[j - 1]);
          if (cj) {
            dist[j] = cjm1 ? dist[j - 1] : d2;
            id[j]   = cjm1 ? id[j - 1]   : cid;
          }
        }
      }
    }
  }
#pragma unroll
  for (int j = 0; j < KNB; j++)
    idxbuf[q * KNB + j] = b * NPTS + id[j];   // store batch-global point id
}

// ---------------------------------------------------------------------------
// K3: qkv GEMM (TOTAL,64) @ (64,192); no bias
// ---------------------------------------------------------------------------
__global__ __launch_bounds__(256) void k_qkv(const float* __restrict__ x,
                                             const float* __restrict__ w,
                                             float* __restrict__ qkv) {
  int gid = blockIdx.x * 256 + threadIdx.x;
  if (gid >= TOTAL * 192) return;
  int p = gid / 192, c = gid % 192;
  const float* xr = x + (size_t)p * 64;
  float acc = 0.f;
#pragma unroll 16
  for (int k = 0; k < 64; k++) acc += xr[k] * w[k * 192 + c];
  qkv[gid] = acc;
}

// ---------------------------------------------------------------------------
// K4: fused point-transformer attention. One block (256 thr) per query point.
//  Phase A: rel-pos MLP (3->64->64), build inp[20][128], vnb[20][64] in LDS
//  Phase B: 20x256 hidden = inp @ aw1 (aw1 staged in 32KB LDS chunks),
//           relu, dot with aw2 -> sim[20] via wave shuffle-reduce
//  Phase C: softmax over 20, weighted sum of vnb -> xout[i][0:64]
// ---------------------------------------------------------------------------
__global__ __launch_bounds__(256) void k_attn(
    const float* __restrict__ pos, const float* __restrict__ qkv,
    const int* __restrict__ idxbuf,
    const float* __restrict__ pw1, const float* __restrict__ pb1,
    const float* __restrict__ pw2, const float* __restrict__ pb2,
    const float* __restrict__ aw1, const float* __restrict__ ab1,
    const float* __restrict__ aw2, const float* __restrict__ ab2,
    float* __restrict__ xout) {
  __shared__ float s_aw1[32 * 256];      // 32 KB chunk of aw1
  __shared__ float s_inp[KNB][128];      // 10 KB
  __shared__ float s_vnb[KNB][64];       // 5 KB
  __shared__ float s_t1[KNB][64];        // 5 KB
  __shared__ float s_qi[64];
  __shared__ float s_sim[KNB];
  __shared__ int s_nb[KNB];

  int i = blockIdx.x;
  int tid = threadIdx.x;
  int lane = tid & 63;
  int wv = tid >> 6;

  if (tid < 64) s_qi[tid] = qkv[(size_t)i * 192 + tid];
  else if (tid < 64 + KNB) s_nb[tid - 64] = idxbuf[i * KNB + (tid - 64)];
  float px = pos[i * 3 + 0], py = pos[i * 3 + 1], pz = pos[i * 3 + 2];
  __syncthreads();

  // A1: t1[n][h] = relu(rel . pw1[:,h] + pb1[h])
  for (int it = tid; it < KNB * 64; it += 256) {
    int n = it >> 6, h = it & 63;
    int g = s_nb[n];
    float rx = px - pos[g * 3 + 0];
    float ry = py - pos[g * 3 + 1];
    float rz = pz - pos[g * 3 + 2];
    float a = pb1[h] + rx * pw1[h] + ry * pw1[64 + h] + rz * pw1[128 + h];
    s_t1[n][h] = fmaxf(a, 0.f);
  }
  __syncthreads();

  // A2: rpe[n][c] = t1[n] . pw2[:,c] + pb2[c]; fill inp & vnb
  for (int it = tid; it < KNB * 64; it += 256) {
    int n = it >> 6, c = it & 63;
    int g = s_nb[n];
    float acc = pb2[c];
#pragma unroll 8
    for (int h = 0; h < 64; h++) acc += s_t1[n][h] * pw2[h * 64 + c];
    float kv = qkv[(size_t)g * 192 + 64 + c];
    float vv = qkv[(size_t)g * 192 + 128 + c];
    s_inp[n][c] = s_qi[c] - kv;
    s_inp[n][64 + c] = acc;
    s_vnb[n][c] = vv + acc;
  }

  // B: hidden (20x256) & sim. wave wv -> neighbors 5*wv..5*wv+4,
  //    lane -> channels 4*lane..4*lane+3
  int nb0 = 5 * wv;
  int c0 = 4 * lane;
  float acc[5][4];
#pragma unroll
  for (int j = 0; j < 5; j++)
#pragma unroll
    for (int cc = 0; cc < 4; cc++) acc[j][cc] = 0.f;

  for (int kc = 0; kc < 128; kc += 32) {
    __syncthreads();  // prior chunk fully consumed (also closes A2 writes)
    for (int j4 = tid * 4; j4 < 32 * 256; j4 += 1024)
      *(float4*)&s_aw1[j4] = *(const float4*)&aw1[kc * 256 + j4];
    __syncthreads();
#pragma unroll
    for (int k4 = 0; k4 < 32; k4 += 4) {
      float4 a0 = *(float4*)&s_aw1[(k4 + 0) * 256 + c0];
      float4 a1 = *(float4*)&s_aw1[(k4 + 1) * 256 + c0];
      float4 a2 = *(float4*)&s_aw1[(k4 + 2) * 256 + c0];
      float4 a3 = *(float4*)&s_aw1[(k4 + 3) * 256 + c0];
#pragma unroll
      for (int j = 0; j < 5; j++) {
        float4 iv = *(float4*)&s_inp[nb0 + j][kc + k4];
        acc[j][0] += iv.x * a0.x + iv.y * a1.x + iv.z * a2.x + iv.w * a3.x;
        acc[j][1] += iv.x * a0.y + iv.y * a1.y + iv.z * a2.y + iv.w * a3.y;
        acc[j][2] += iv.x * a0.z + iv.y * a1.z + iv.z * a2.z + iv.w * a3.z;
        acc[j][3] += iv.x * a0.w + iv.y * a1.w + iv.z * a2.w + iv.w * a3.w;
      }
    }
  }

  // epilogue: relu(+ab1) . aw2, wave butterfly reduce over 64 lanes
  float4 b1 = *(const float4*)&ab1[c0];
  float4 w2 = *(const float4*)&aw2[c0];
  float s[5];
#pragma unroll
  for (int j = 0; j < 5; j++) {
    s[j] = fmaxf(acc[j][0] + b1.x, 0.f) * w2.x +
           fmaxf(acc[j][1] + b1.y, 0.f) * w2.y +
           fmaxf(acc[j][2] + b1.z, 0.f) * w2.z +
           fmaxf(acc[j][3] + b1.w, 0.f) * w2.w;
  }
#pragma unroll
  for (int off = 32; off > 0; off >>= 1)
#pragma unroll
    for (int j = 0; j < 5; j++) s[j] += __shfl_xor(s[j], off);
  if (lane == 0) {
#pragma unroll
    for (int j = 0; j < 5; j++) s_sim[nb0 + j] = s[j] + ab2[0];
  }
  __syncthreads();

  // C: softmax over K, weighted sum of vnb
  if (tid < 64) {
    float mx = -3.402823466e38f;
#pragma unroll
    for (int n = 0; n < KNB; n++) mx = fmaxf(mx, s_sim[n]);
    float e[KNB];
    float sum = 0.f;
#pragma unroll
    for (int n = 0; n < KNB; n++) { e[n] = expf(s_sim[n] - mx); sum += e[n]; }
    float inv = 1.f / sum;
    float o = 0.f;
#pragma unroll
    for (int n = 0; n < KNB; n++) o += (e[n] * inv) * s_vnb[n][tid];
    xout[(size_t)i * 64 + tid] = o;
  }
}

// ---------------------------------------------------------------------------
// K5: global max-pool over N, fc1(64->32)+relu, fc3(32->3). One block/batch.
// ---------------------------------------------------------------------------
__global__ __launch_bounds__(256) void k_final(const float* __restrict__ x,
                                               const float* __restrict__ fc1w,
                                               const float* __restrict__ fc1b,
                                               const float* __restrict__ fc3w,
                                               const float* __restrict__ fc3b,
                                               float* __restrict__ out) {
  __shared__ float red[4][64];
  __shared__ float m[64];
  __shared__ float h1[32];
  int b = blockIdx.x;
  int tid = threadIdx.x;
  int c = tid & 63, pg = tid >> 6;
  float mx = -3.402823466e38f;
  for (int p = pg; p < NPTS; p += 4)
    mx = fmaxf(mx, x[((size_t)b * NPTS + p) * 64 + c]);
  red[pg][c] = mx;
  __syncthreads();
  if (tid < 64)
    m[c] = fmaxf(fmaxf(red[0][c], red[1][c]), fmaxf(red[2][c], red[3][c]));
  __syncthreads();
  if (tid < 32) {
    float a = fc1b[tid];
#pragma unroll 8
    for (int k = 0; k < 64; k++) a += m[k] * fc1w[k * 32 + tid];
    h1[tid] = fmaxf(a, 0.f);
  }
  __syncthreads();
  if (tid < 3) {
    float a = fc3b[tid];
#pragma unroll
    for (int k = 0; k < 32; k++) a += h1[k] * fc3w[k * 3 + tid];
    out[b * 3 + tid] = a;
  }
}

// ---------------------------------------------------------------------------
extern "C" void kernel_launch(void* const* d_in, const int* in_sizes, int n_in,
                              void* d_out, int out_size, void* d_ws,
                              size_t ws_size, hipStream_t stream) {
  const float* pts    = (const float*)d_in[0];
  const float* conv_w = (const float*)d_in[1];
  const float* conv_b = (const float*)d_in[2];
  // layer weight index bases: l1 -> 3, l2 -> 12
  const float* fc1w = (const float*)d_in[21];
  const float* fc1b = (const float*)d_in[22];
  const float* fc3w = (const float*)d_in[23];
  const float* fc3b = (const float*)d_in[24];
  float* outp = (float*)d_out;

  char* ws = (char*)d_ws;
  float* x0  = (float*)(ws);                        // 16384*64
  float* qkv = (float*)(ws + (size_t)4 * 1024 * 1024);   // 16384*192
  int*   idx = (int*)  (ws + (size_t)17 * 1024 * 1024);  // 16384*20
  float* x1  = (float*)(ws + (size_t)19 * 1024 * 1024);  // 16384*64
  float* x2  = (float*)(ws + (size_t)24 * 1024 * 1024);  // 16384*64

  k_conv<<<(TOTAL * 64 + 255) / 256, 256, 0, stream>>>(pts, conv_w, conv_b, x0);
  k_knn<<<TOTAL / 256, 256, 0, stream>>>(pts, idx);

  // layer 1
  {
    const float* qkvw = (const float*)d_in[3];
    k_qkv<<<(TOTAL * 192 + 255) / 256, 256, 0, stream>>>(x0, qkvw, qkv);
    k_attn<<<TOTAL, 256, 0, stream>>>(
        pts, qkv, idx, (const float*)d_in[4], (const float*)d_in[5],
        (const float*)d_in[6], (const float*)d_in[7], (const float*)d_in[8],
        (const float*)d_in[9], (const float*)d_in[10], (const float*)d_in[11],
        x1);
  }
  // layer 2
  {
    const float* qkvw = (const float*)d_in[12];
    k_qkv<<<(TOTAL * 192 + 255) / 256, 256, 0, stream>>>(x1, qkvw, qkv);
    k_attn<<<TOTAL, 256, 0, stream>>>(
        pts, qkv, idx, (const float*)d_in[13], (const float*)d_in[14],
        (const float*)d_in[15], (const float*)d_in[16], (const float*)d_in[17],
        (const float*)d_in[18], (const float*)d_in[19], (const float*)d_in[20],
        x2);
  }
  k_final<<<BATCH, 256, 0, stream>>>(x2, fc1w, fc1b, fc3w, fc3b, outp);
}

// Round 2
// 2501.200 us; speedup vs baseline: 1.7801x; 1.7801x over previous
//
#include <hip/hip_runtime.h>
#include <cstdint>
#include <cstddef>

#define KNB 20
#define NPTS 8192
#define BATCH 2
#define TOTAL (BATCH * NPTS)
#define SPLITS 8
#define CPS (NPTS / SPLITS)   // 1024 candidates per split

// ---------------------------------------------------------------------------
// K1: pointwise conv 3->64 + relu
// ---------------------------------------------------------------------------
__global__ __launch_bounds__(256) void k_conv(const float* __restrict__ pts,
                                              const float* __restrict__ w,
                                              const float* __restrict__ b,
                                              float* __restrict__ x0) {
  int gid = blockIdx.x * 256 + threadIdx.x;
  if (gid >= TOTAL * 64) return;
  int p = gid >> 6, c = gid & 63;
  float px = pts[p * 3 + 0], py = pts[p * 3 + 1], pz = pts[p * 3 + 2];
  float acc = b[c] + px * w[c] + py * w[64 + c] + pz * w[128 + c];
  x0[gid] = fmaxf(acc, 0.f);
}

// ---------------------------------------------------------------------------
// K2a: partial KNN. Block (qb, s): queries qb*256..+255 (one per thread),
// candidate range [s*1024, (s+1)*1024) staged in LDS. Per-thread exact
// top-20 via the same branchless sorted insert that benched bit-exact.
// Output: part[q][s][j] = (dist, idx_in_batch) as float2.
// ---------------------------------------------------------------------------
__global__ __launch_bounds__(256) void k_knn_part(const float* __restrict__ pts,
                                                  float2* __restrict__ part) {
  __shared__ float sx[CPS], sy[CPS], sz[CPS];
  int tid = threadIdx.x;
  int qb = blockIdx.x;      // 0..63
  int s = blockIdx.y;       // 0..SPLITS-1
  int q = qb * 256 + tid;   // block-uniform batch (256 | 8192)
  int b = q >> 13;
  const float* pbase = pts + (size_t)b * NPTS * 3;
  const float* cbase = pbase + (size_t)s * CPS * 3;

  for (int c = tid; c < CPS; c += 256) {
    sx[c] = cbase[c * 3 + 0];
    sy[c] = cbase[c * 3 + 1];
    sz[c] = cbase[c * 3 + 2];
  }
  float qx = pts[q * 3 + 0], qy = pts[q * 3 + 1], qz = pts[q * 3 + 2];
  __syncthreads();

  float dist[KNB];
  int id[KNB];
#pragma unroll
  for (int j = 0; j < KNB; j++) { dist[j] = 3.402823466e38f; id[j] = 0; }

  int cid0 = s * CPS;
  for (int c = 0; c < CPS; c++) {
    float dx = qx - sx[c];
    float dy = qy - sy[c];
    float dz = qz - sz[c];
    float d2 = dx * dx + dy * dy + dz * dz;
    if (d2 < dist[KNB - 1]) {
      int cid = cid0 + c;
      // branchless sorted insert (ascending); strict < keeps lax.top_k
      // stable tie-breaking (earlier index wins).
#pragma unroll
      for (int j = KNB - 1; j >= 0; j--) {
        bool cj = d2 < dist[j];
        bool cjm1 = (j > 0) && (d2 < dist[j - 1]);
        if (cj) {
          dist[j] = cjm1 ? dist[j - 1] : d2;
          id[j]   = cjm1 ? id[j - 1]   : cid;
        }
      }
    }
  }

  float2* dst = part + ((size_t)q * SPLITS + s) * KNB;
#pragma unroll
  for (int j = 0; j < KNB; j++)
    dst[j] = make_float2(dist[j], __int_as_float(id[j]));
}

// ---------------------------------------------------------------------------
// K2b: merge SPLITS sorted lists of 20 -> global top-20 per query.
// Block: 32 queries x 8 splits. 8 threads stage lists into LDS; thread s==0
// runs the 8-way tournament (strict <, ascending split order == ascending
// index ranges -> exact lax.top_k tie order).
// ---------------------------------------------------------------------------
__global__ __launch_bounds__(256) void k_knn_merge(const float2* __restrict__ part,
                                                   int* __restrict__ idxbuf) {
  __shared__ float sd[32][SPLITS][KNB];
  __shared__ int   si[32][SPLITS][KNB];
  __shared__ int   sp[32][SPLITS];
  int tid = threadIdx.x;
  int lq = tid >> 3, s = tid & 7;
  int q = blockIdx.x * 32 + lq;

  const float2* src = part + ((size_t)q * SPLITS + s) * KNB;
#pragma unroll
  for (int j = 0; j < KNB; j++) {
    float2 v = src[j];
    sd[lq][s][j] = v.x;
    si[lq][s][j] = __float_as_int(v.y);
  }
  sp[lq][s] = 0;
  __syncthreads();

  if (s == 0) {
    int bq = q >> 13;
    for (int step = 0; step < KNB; step++) {
      float best = 3.402823466e38f;
      int bs = 0, bi = 0;
      for (int s2 = 0; s2 < SPLITS; s2++) {
        int p = sp[lq][s2];
        float d = sd[lq][s2][p];
        if (d < best) { best = d; bs = s2; bi = si[lq][s2][p]; }
      }
      sp[lq][bs]++;
      idxbuf[q * KNB + step] = bq * NPTS + bi;
    }
  }
}

// ---------------------------------------------------------------------------
// K3: qkv GEMM (TOTAL,64) @ (64,192); no bias
// ---------------------------------------------------------------------------
__global__ __launch_bounds__(256) void k_qkv(const float* __restrict__ x,
                                             const float* __restrict__ w,
                                             float* __restrict__ qkv) {
  int gid = blockIdx.x * 256 + threadIdx.x;
  if (gid >= TOTAL * 192) return;
  int p = gid / 192, c = gid % 192;
  const float* xr = x + (size_t)p * 64;
  float acc = 0.f;
#pragma unroll 16
  for (int k = 0; k < 64; k++) acc += xr[k] * w[k * 192 + c];
  qkv[gid] = acc;
}

// ---------------------------------------------------------------------------
// K4: fused point-transformer attention. One block (256 thr) per query point.
// ---------------------------------------------------------------------------
__global__ __launch_bounds__(256) void k_attn(
    const float* __restrict__ pos, const float* __restrict__ qkv,
    const int* __restrict__ idxbuf,
    const float* __restrict__ pw1, const float* __restrict__ pb1,
    const float* __restrict__ pw2, const float* __restrict__ pb2,
    const float* __restrict__ aw1, const float* __restrict__ ab1,
    const float* __restrict__ aw2, const float* __restrict__ ab2,
    float* __restrict__ xout) {
  __shared__ float s_aw1[32 * 256];      // 32 KB chunk of aw1
  __shared__ float s_inp[KNB][128];      // 10 KB
  __shared__ float s_vnb[KNB][64];       // 5 KB
  __shared__ float s_t1[KNB][64];        // 5 KB
  __shared__ float s_qi[64];
  __shared__ float s_sim[KNB];
  __shared__ int s_nb[KNB];

  int i = blockIdx.x;
  int tid = threadIdx.x;
  int lane = tid & 63;
  int wv = tid >> 6;

  if (tid < 64) s_qi[tid] = qkv[(size_t)i * 192 + tid];
  else if (tid < 64 + KNB) s_nb[tid - 64] = idxbuf[i * KNB + (tid - 64)];
  float px = pos[i * 3 + 0], py = pos[i * 3 + 1], pz = pos[i * 3 + 2];
  __syncthreads();

  // A1: t1[n][h] = relu(rel . pw1[:,h] + pb1[h])
  for (int it = tid; it < KNB * 64; it += 256) {
    int n = it >> 6, h = it & 63;
    int g = s_nb[n];
    float rx = px - pos[g * 3 + 0];
    float ry = py - pos[g * 3 + 1];
    float rz = pz - pos[g * 3 + 2];
    float a = pb1[h] + rx * pw1[h] + ry * pw1[64 + h] + rz * pw1[128 + h];
    s_t1[n][h] = fmaxf(a, 0.f);
  }
  __syncthreads();

  // A2: rpe[n][c] = t1[n] . pw2[:,c] + pb2[c]; fill inp & vnb
  for (int it = tid; it < KNB * 64; it += 256) {
    int n = it >> 6, c = it & 63;
    int g = s_nb[n];
    float acc = pb2[c];
#pragma unroll 8
    for (int h = 0; h < 64; h++) acc += s_t1[n][h] * pw2[h * 64 + c];
    float kv = qkv[(size_t)g * 192 + 64 + c];
    float vv = qkv[(size_t)g * 192 + 128 + c];
    s_inp[n][c] = s_qi[c] - kv;
    s_inp[n][64 + c] = acc;
    s_vnb[n][c] = vv + acc;
  }

  // B: hidden (20x256) & sim. wave wv -> neighbors 5*wv..5*wv+4,
  //    lane -> channels 4*lane..4*lane+3
  int nb0 = 5 * wv;
  int c0 = 4 * lane;
  float acc[5][4];
#pragma unroll
  for (int j = 0; j < 5; j++)
#pragma unroll
    for (int cc = 0; cc < 4; cc++) acc[j][cc] = 0.f;

  for (int kc = 0; kc < 128; kc += 32) {
    __syncthreads();  // prior chunk fully consumed (also closes A2 writes)
    for (int j4 = tid * 4; j4 < 32 * 256; j4 += 1024)
      *(float4*)&s_aw1[j4] = *(const float4*)&aw1[kc * 256 + j4];
    __syncthreads();
#pragma unroll
    for (int k4 = 0; k4 < 32; k4 += 4) {
      float4 a0 = *(float4*)&s_aw1[(k4 + 0) * 256 + c0];
      float4 a1 = *(float4*)&s_aw1[(k4 + 1) * 256 + c0];
      float4 a2 = *(float4*)&s_aw1[(k4 + 2) * 256 + c0];
      float4 a3 = *(float4*)&s_aw1[(k4 + 3) * 256 + c0];
#pragma unroll
      for (int j = 0; j < 5; j++) {
        float4 iv = *(float4*)&s_inp[nb0 + j][kc + k4];
        acc[j][0] += iv.x * a0.x + iv.y * a1.x + iv.z * a2.x + iv.w * a3.x;
        acc[j][1] += iv.x * a0.y + iv.y * a1.y + iv.z * a2.y + iv.w * a3.y;
        acc[j][2] += iv.x * a0.z + iv.y * a1.z + iv.z * a2.z + iv.w * a3.z;
        acc[j][3] += iv.x * a0.w + iv.y * a1.w + iv.z * a2.w + iv.w * a3.w;
      }
    }
  }

  // epilogue: relu(+ab1) . aw2, wave butterfly reduce over 64 lanes
  float4 b1 = *(const float4*)&ab1[c0];
  float4 w2 = *(const float4*)&aw2[c0];
  float s[5];
#pragma unroll
  for (int j = 0; j < 5; j++) {
    s[j] = fmaxf(acc[j][0] + b1.x, 0.f) * w2.x +
           fmaxf(acc[j][1] + b1.y, 0.f) * w2.y +
           fmaxf(acc[j][2] + b1.z, 0.f) * w2.z +
           fmaxf(acc[j][3] + b1.w, 0.f) * w2.w;
  }
#pragma unroll
  for (int off = 32; off > 0; off >>= 1)
#pragma unroll
    for (int j = 0; j < 5; j++) s[j] += __shfl_xor(s[j], off);
  if (lane == 0) {
#pragma unroll
    for (int j = 0; j < 5; j++) s_sim[nb0 + j] = s[j] + ab2[0];
  }
  __syncthreads();

  // C: softmax over K, weighted sum of vnb
  if (tid < 64) {
    float mx = -3.402823466e38f;
#pragma unroll
    for (int n = 0; n < KNB; n++) mx = fmaxf(mx, s_sim[n]);
    float e[KNB];
    float sum = 0.f;
#pragma unroll
    for (int n = 0; n < KNB; n++) { e[n] = expf(s_sim[n] - mx); sum += e[n]; }
    float inv = 1.f / sum;
    float o = 0.f;
#pragma unroll
    for (int n = 0; n < KNB; n++) o += (e[n] * inv) * s_vnb[n][tid];
    xout[(size_t)i * 64 + tid] = o;
  }
}

// ---------------------------------------------------------------------------
// K5: global max-pool over N, fc1(64->32)+relu, fc3(32->3). One block/batch.
// ---------------------------------------------------------------------------
__global__ __launch_bounds__(256) void k_final(const float* __restrict__ x,
                                               const float* __restrict__ fc1w,
                                               const float* __restrict__ fc1b,
                                               const float* __restrict__ fc3w,
                                               const float* __restrict__ fc3b,
                                               float* __restrict__ out) {
  __shared__ float red[4][64];
  __shared__ float m[64];
  __shared__ float h1[32];
  int b = blockIdx.x;
  int tid = threadIdx.x;
  int c = tid & 63, pg = tid >> 6;
  float mx = -3.402823466e38f;
  for (int p = pg; p < NPTS; p += 4)
    mx = fmaxf(mx, x[((size_t)b * NPTS + p) * 64 + c]);
  red[pg][c] = mx;
  __syncthreads();
  if (tid < 64)
    m[c] = fmaxf(fmaxf(red[0][c], red[1][c]), fmaxf(red[2][c], red[3][c]));
  __syncthreads();
  if (tid < 32) {
    float a = fc1b[tid];
#pragma unroll 8
    for (int k = 0; k < 64; k++) a += m[k] * fc1w[k * 32 + tid];
    h1[tid] = fmaxf(a, 0.f);
  }
  __syncthreads();
  if (tid < 3) {
    float a = fc3b[tid];
#pragma unroll
    for (int k = 0; k < 32; k++) a += h1[k] * fc3w[k * 3 + tid];
    out[b * 3 + tid] = a;
  }
}

// ---------------------------------------------------------------------------
// Workspace layout (bytes), peak 28.3 MB (same footprint as the passing run):
//   x0   @ 0        (4.19 MB)   live: conv -> qkv(l1)
//   idx  @ 4 MB     (1.31 MB)   live: merge -> attn(l2)
//   part @ 6 MB     (20.97 MB)  live: part -> merge   } overlapped:
//   qkv  @ 6 MB     (12.58 MB)  live: qkv -> attn     } part dead first
//   x1   @ 19 MB    (4.19 MB)   live: attn1 -> qkv(l2)
//   x2   @ 23 MB+   (4.19 MB)   live: attn2 -> final
// ---------------------------------------------------------------------------
extern "C" void kernel_launch(void* const* d_in, const int* in_sizes, int n_in,
                              void* d_out, int out_size, void* d_ws,
                              size_t ws_size, hipStream_t stream) {
  const float* pts    = (const float*)d_in[0];
  const float* conv_w = (const float*)d_in[1];
  const float* conv_b = (const float*)d_in[2];
  const float* fc1w = (const float*)d_in[21];
  const float* fc1b = (const float*)d_in[22];
  const float* fc3w = (const float*)d_in[23];
  const float* fc3b = (const float*)d_in[24];
  float* outp = (float*)d_out;

  char* ws = (char*)d_ws;
  float*  x0   = (float*) (ws);
  int*    idx  = (int*)   (ws + (size_t)4 * 1048576);
  float2* part = (float2*)(ws + (size_t)6 * 1048576);
  float*  qkv  = (float*) (ws + (size_t)6 * 1048576);   // reuses part region
  float*  x1   = (float*) (ws + (size_t)19 * 1048576);
  float*  x2   = (float*) (ws + (size_t)19 * 1048576 + 4194304);

  k_conv<<<(TOTAL * 64 + 255) / 256, 256, 0, stream>>>(pts, conv_w, conv_b, x0);
  k_knn_part<<<dim3(TOTAL / 256, SPLITS), 256, 0, stream>>>(pts, part);
  k_knn_merge<<<TOTAL / 32, 256, 0, stream>>>(part, idx);

  // layer 1
  {
    const float* qkvw = (const float*)d_in[3];
    k_qkv<<<(TOTAL * 192 + 255) / 256, 256, 0, stream>>>(x0, qkvw, qkv);
    k_attn<<<TOTAL, 256, 0, stream>>>(
        pts, qkv, idx, (const float*)d_in[4], (const float*)d_in[5],
        (const float*)d_in[6], (const float*)d_in[7], (const float*)d_in[8],
        (const float*)d_in[9], (const float*)d_in[10], (const float*)d_in[11],
        x1);
  }
  // layer 2
  {
    const float* qkvw = (const float*)d_in[12];
    k_qkv<<<(TOTAL * 192 + 255) / 256, 256, 0, stream>>>(x1, qkvw, qkv);
    k_attn<<<TOTAL, 256, 0, stream>>>(
        pts, qkv, idx, (const float*)d_in[13], (const float*)d_in[14],
        (const float*)d_in[15], (const float*)d_in[16], (const float*)d_in[17],
        (const float*)d_in[18], (const float*)d_in[19], (const float*)d_in[20],
        x2);
  }
  k_final<<<BATCH, 256, 0, stream>>>(x2, fc1w, fc1b, fc3w, fc3b, outp);
}